// Round 2
// 853.026 us; speedup vs baseline: 1.0919x; 1.0919x over previous
//
#include <hip/hip_runtime.h>

typedef unsigned short u16;
typedef __attribute__((ext_vector_type(8))) __bf16 bf16x8;
typedef __attribute__((ext_vector_type(8))) unsigned short u16x8;
typedef __attribute__((ext_vector_type(4))) float f32x4;

#define AS1 __attribute__((address_space(1)))
#define AS3 __attribute__((address_space(3)))

__device__ __forceinline__ void load_lds16(const void* g, void* l) {
  __builtin_amdgcn_global_load_lds((const AS1 unsigned int*)g,
                                   (AS3 unsigned int*)l, 16, 0, 0);
}

__device__ __forceinline__ float bf2f(u16 u) {
  unsigned int x = ((unsigned int)u) << 16;
  return __builtin_bit_cast(float, x);
}
__device__ __forceinline__ u16 f2bf(float f) {
  unsigned int x = __builtin_bit_cast(unsigned int, f);
  x += 0x7fffu + ((x >> 16) & 1u);
  return (u16)(x >> 16);
}
// load 8 consecutive f32, RNE-convert to bf16x8
__device__ __forceinline__ bf16x8 cvt8(const float* p) {
  f32x4 a = *(const f32x4*)p;
  f32x4 b = *(const f32x4*)(p + 4);
  u16x8 r;
#pragma unroll
  for (int j = 0; j < 4; ++j) { r[j] = f2bf(a[j]); r[4 + j] = f2bf(b[j]); }
  return __builtin_bit_cast(bf16x8, r);
}

// ---------------------------------------------------------------- weight transpose
// out[c - col0][r] = bf16(in[r*C + c])  for c in [col0, col0+Cpanel)
// 32x33-padded LDS tile: conflict-free.
__global__ __launch_bounds__(256) void transpose_w(const float* __restrict__ in,
                                                   u16* __restrict__ out,
                                                   int R, int C, int col0) {
  __shared__ u16 tile[32][33];
  const int tx = threadIdx.x & 31, ty = threadIdx.x >> 5;
  const int c0 = blockIdx.x * 32, r0 = blockIdx.y * 32;  // c0: panel-local col
#pragma unroll
  for (int j = ty; j < 32; j += 8)
    tile[j][tx] = f2bf(in[(size_t)(r0 + j) * C + col0 + c0 + tx]);
  __syncthreads();
#pragma unroll
  for (int j = ty; j < 32; j += 8)
    out[(size_t)(c0 + j) * R + r0 + tx] = tile[tx][j];
}

// ---------------------------------------------------------------- GEMM (m97 structure)
// C[M,N] = A[M,K] @ Bt[N,K]^T.  A: f32 (AF32=1, converted in-staging) or bf16
// (AF32=0, global_load_lds).  B: bf16 [N,K] via global_load_lds width-16.
// OF32: C dtype.  TR: write C[col*ldC + row] (transposed).  128x128 tile, BK=32.
template <int AF32, int OF32, int TR>
__global__ __launch_bounds__(256) void gemm_bt(const void* __restrict__ Av,
                                               const u16* __restrict__ Bt,
                                               void* __restrict__ Cv,
                                               int M, int N, int K, int ldC) {
  __shared__ __align__(16) u16 As[128 * 32];
  __shared__ __align__(16) u16 Bs[128 * 32];
  const int tid = threadIdx.x, lane = tid & 63, w = tid >> 6;
  const int quad = lane >> 4, c16 = lane & 15;
  const int rw = lane >> 2, c4 = lane & 3;
  const int bm = blockIdx.x * 128, bn = blockIdx.y * 128;
  const int wm = (w >> 1) * 64, wn = (w & 1) * 64;

  f32x4 acc[4][4] = {};

  const u16* Ab = (const u16*)Av;
  const float* Af = (const float*)Av;
  const u16* Ag0 = Ab + (size_t)(bm + w * 16 + rw) * K + c4 * 8;
  const u16* Ag1 = Ag0 + (size_t)64 * K;
  const float* Af0 = Af + (size_t)(bm + w * 16 + rw) * K + c4 * 8;
  const float* Af1 = Af0 + (size_t)64 * K;
  const u16* Bg0 = Bt + (size_t)(bn + w * 16 + rw) * K + c4 * 8;
  const u16* Bg1 = Bg0 + (size_t)64 * K;
  u16* As0 = &As[(w * 16) * 32];
  u16* As1 = &As[(64 + w * 16) * 32];
  u16* Bs0 = &Bs[(w * 16) * 32];
  u16* Bs1 = &Bs[(64 + w * 16) * 32];

  for (int k0 = 0; k0 < K; k0 += 32) {
    bf16x8 va0, va1;
    if (AF32) {  // register prefetch + convert (issue before DMA)
      va0 = cvt8(Af0 + k0);
      va1 = cvt8(Af1 + k0);
    } else {
      load_lds16(Ag0 + k0, As0);
      load_lds16(Ag1 + k0, As1);
    }
    load_lds16(Bg0 + k0, Bs0);
    load_lds16(Bg1 + k0, Bs1);
    if (AF32) {  // vectorized b128 writes, conflict-free [row][32] layout
      *(bf16x8*)&As[(w * 16 + rw) * 32 + c4 * 8] = va0;
      *(bf16x8*)&As[(64 + w * 16 + rw) * 32 + c4 * 8] = va1;
    }
    __syncthreads();  // drains vmcnt (DMA) + lgkm (ds_write) before reads
    bf16x8 a[4], b[4];
#pragma unroll
    for (int mt = 0; mt < 4; ++mt)
      a[mt] = *(const bf16x8*)&As[(wm + mt * 16 + c16) * 32 + quad * 8];
#pragma unroll
    for (int nt = 0; nt < 4; ++nt)
      b[nt] = *(const bf16x8*)&Bs[(wn + nt * 16 + c16) * 32 + quad * 8];
#pragma unroll
    for (int mt = 0; mt < 4; ++mt)
#pragma unroll
      for (int nt = 0; nt < 4; ++nt)
        acc[mt][nt] = __builtin_amdgcn_mfma_f32_16x16x32_bf16(a[mt], b[nt], acc[mt][nt], 0, 0, 0);
    __syncthreads();  // all waves done with tiles before next DMA lands
  }
#pragma unroll
  for (int mt = 0; mt < 4; ++mt)
#pragma unroll
    for (int nt = 0; nt < 4; ++nt)
#pragma unroll
      for (int r = 0; r < 4; ++r) {
        const int row = bm + wm + mt * 16 + quad * 4 + r;
        const int col = bn + wn + nt * 16 + c16;
        const size_t idx = TR ? (size_t)col * ldC + row : (size_t)row * ldC + col;
        if (OF32)
          ((float*)Cv)[idx] = acc[mt][nt][r];
        else
          ((u16*)Cv)[idx] = f2bf(acc[mt][nt][r]);
      }
}

// ---------------------------------------------------------------- RoPE (in place, bf16)
__global__ void rope_kernel(u16* __restrict__ buf, const int* __restrict__ pos,
                            int log2nh, float oscale) {
  const int t = blockIdx.x * 256 + threadIdx.x;
  const int i = t & 63;
  const int h = (t >> 6) & ((1 << log2nh) - 1);
  const int s = t >> (6 + log2nh);
  const int nh = 1 << log2nh;
  const float p = (float)pos[s];
  const float invf = exp2f((float)i * -0.20762051915861040f);  // 10000^(-i/64)
  const float ang = p * invf;
  const float cn = cosf(ang), sn = sinf(ang);
  const size_t i1 = (size_t)s * (nh * 128) + h * 128 + i;
  const size_t i2 = i1 + 64;
  const float x1 = bf2f(buf[i1]), x2 = bf2f(buf[i2]);
  buf[i1] = f2bf((x1 * cn - x2 * sn) * oscale);
  buf[i2] = f2bf((x2 * cn + x1 * sn) * oscale);
}

// ---------------------------------------------------------------- flash attention
// Q: [S,32*128] bf16 (RoPE'd, pre-scaled 1/sqrt(128));  K: [S,8*128] bf16
// VT: [8*128, S] bf16;  O: [S,32*128] bf16.
// v2: block = 2 paired q-tiles (qb, 31-qb) x 1 head -> 33 iters/block, zero
// tail.  Q direct-to-reg (no Qs LDS).  K/V reg-prefetch pipeline (loads for
// t+1 issue before compute(t)).  Ks [key][128] / Vts [d][64] with XOR swizzle
// (u16col ^= (row&7)<<3): fragment ds_read_b128 spreads 16 lanes over all 8
// 16B slots -> 2 lanes/bank-slot = conflict-free (write side uses the same
// involution).
__global__ __launch_bounds__(256, 2) void flash_kernel(const u16* __restrict__ Q,
                                                       const u16* __restrict__ K,
                                                       const u16* __restrict__ VT,
                                                       u16* __restrict__ O) {
  __shared__ __align__(16) u16 Ks[64 * 128];   // [key][k], swizzled
  __shared__ __align__(16) u16 Vts[128 * 64];  // [d][key], swizzled
  __shared__ __align__(16) u16 Ps[4][16 * 72]; // per-wave P tile (2-way = free)
  const int h = blockIdx.y, kvh = h >> 2;
  const int tid = threadIdx.x, lane = tid & 63, w = tid >> 6;
  const int quad = lane >> 4, c16 = lane & 15;
  const int rw = lane >> 2, c4 = lane & 3;
  const int sw = (rw & 7) << 3;   // write-side swizzle (row = w*16+rw)
  const int sr = (c16 & 7) << 3;  // read-side swizzle (row = nt*16+c16 / dt*16+c16)

  for (int half = 0; half < 2; ++half) {
    const int qb = half ? (31 - blockIdx.x) : blockIdx.x;

    // Q fragments straight from global (16 KB/block, once per half)
    bf16x8 aq[4];
#pragma unroll
    for (int kc = 0; kc < 4; ++kc)
      aq[kc] = *(const bf16x8*)&Q[(size_t)(qb * 64 + w * 16 + c16) * 4096 + h * 128 + kc * 32 + quad * 8];

    f32x4 acc_o[8] = {};
    float m_run[4], l_run[4];
#pragma unroll
    for (int r = 0; r < 4; ++r) { m_run[r] = -1e30f; l_run[r] = 0.f; }

    // prologue: tile 0 into regs
    bf16x8 kc_[4], vc_[4];
#pragma unroll
    for (int p = 0; p < 4; ++p) {
      kc_[p] = *(const bf16x8*)&K[(size_t)(w * 16 + rw) * 1024 + kvh * 128 + p * 32 + c4 * 8];
      const int d = (p & 1) * 64 + w * 16 + rw;
      vc_[p] = *(const bf16x8*)&VT[(size_t)(kvh * 128 + d) * 2048 + (p >> 1) * 32 + c4 * 8];
    }

    for (int t = 0; t <= qb; ++t) {
      __syncthreads();  // all waves done reading LDS of previous tile
      const int key = w * 16 + rw;
#pragma unroll
      for (int p = 0; p < 4; ++p) {
        *(bf16x8*)&Ks[key * 128 + ((p * 32 + c4 * 8) ^ sw)] = kc_[p];
        const int d = (p & 1) * 64 + w * 16 + rw;
        *(bf16x8*)&Vts[d * 64 + ((((p >> 1) * 32 + c4 * 8)) ^ ((d & 7) << 3))] = vc_[p];
      }
      __syncthreads();  // tile visible to all waves
      if (t < qb) {     // prefetch t+1: latency hides under compute below
#pragma unroll
        for (int p = 0; p < 4; ++p) {
          kc_[p] = *(const bf16x8*)&K[(size_t)((t + 1) * 64 + w * 16 + rw) * 1024 + kvh * 128 + p * 32 + c4 * 8];
          const int d = (p & 1) * 64 + w * 16 + rw;
          vc_[p] = *(const bf16x8*)&VT[(size_t)(kvh * 128 + d) * 2048 + (t + 1) * 64 + (p >> 1) * 32 + c4 * 8];
        }
      }

      f32x4 sacc[4];
#pragma unroll
      for (int nt = 0; nt < 4; ++nt) {
        f32x4 s = {0.f, 0.f, 0.f, 0.f};
#pragma unroll
        for (int kc = 0; kc < 4; ++kc) {
          bf16x8 bk = *(const bf16x8*)&Ks[(nt * 16 + c16) * 128 + ((kc * 32 + quad * 8) ^ sr)];
          s = __builtin_amdgcn_mfma_f32_16x16x32_bf16(aq[kc], bk, s, 0, 0, 0);
        }
        sacc[nt] = s;
      }
      if (t == qb) {
#pragma unroll
        for (int nt = 0; nt < 4; ++nt)
#pragma unroll
          for (int r = 0; r < 4; ++r)
            if (nt * 16 + c16 > w * 16 + quad * 4 + r) sacc[nt][r] = -1e30f;
      }
      float al[4];
#pragma unroll
      for (int r = 0; r < 4; ++r) {
        float mx = fmaxf(fmaxf(sacc[0][r], sacc[1][r]), fmaxf(sacc[2][r], sacc[3][r]));
#pragma unroll
        for (int off = 1; off < 16; off <<= 1) mx = fmaxf(mx, __shfl_xor(mx, off));
        const float nm = fmaxf(m_run[r], mx);
        al[r] = __expf(m_run[r] - nm);
        m_run[r] = nm;
        float sum = 0.f;
#pragma unroll
        for (int nt = 0; nt < 4; ++nt) {
          const float pv = __expf(sacc[nt][r] - nm);
          sacc[nt][r] = pv;
          sum += pv;
        }
#pragma unroll
        for (int off = 1; off < 16; off <<= 1) sum += __shfl_xor(sum, off);
        l_run[r] = l_run[r] * al[r] + sum;
      }
#pragma unroll
      for (int dt = 0; dt < 8; ++dt)
#pragma unroll
        for (int r = 0; r < 4; ++r) acc_o[dt][r] *= al[r];
#pragma unroll
      for (int nt = 0; nt < 4; ++nt)
#pragma unroll
        for (int r = 0; r < 4; ++r)
          Ps[w][(quad * 4 + r) * 72 + nt * 16 + c16] = f2bf(sacc[nt][r]);
      asm volatile("s_waitcnt lgkmcnt(0)" ::: "memory");
      bf16x8 ap[2];
#pragma unroll
      for (int kc = 0; kc < 2; ++kc)
        ap[kc] = *(const bf16x8*)&Ps[w][c16 * 72 + kc * 32 + quad * 8];
#pragma unroll
      for (int dt = 0; dt < 8; ++dt)
#pragma unroll
        for (int kc = 0; kc < 2; ++kc) {
          bf16x8 bv = *(const bf16x8*)&Vts[(dt * 16 + c16) * 64 + ((kc * 32 + quad * 8) ^ sr)];
          acc_o[dt] = __builtin_amdgcn_mfma_f32_16x16x32_bf16(ap[kc], bv, acc_o[dt], 0, 0, 0);
        }
    }
#pragma unroll
    for (int r = 0; r < 4; ++r) {
      const float inv = 1.0f / l_run[r];
      const int row = qb * 64 + w * 16 + quad * 4 + r;
#pragma unroll
      for (int dt = 0; dt < 8; ++dt)
        O[(size_t)row * 4096 + h * 128 + dt * 16 + c16] = f2bf(acc_o[dt][r] * inv);
    }
  }
}

// ---------------------------------------------------------------- launch
extern "C" void kernel_launch(void* const* d_in, const int* in_sizes, int n_in,
                              void* d_out, int out_size, void* d_ws, size_t ws_size,
                              hipStream_t stream) {
  const float* X  = (const float*)d_in[0];   // [2048,4096] f32
  const int* pos  = (const int*)d_in[2];     // causal mask (d_in[1]) applied analytically
  const float* Wq = (const float*)d_in[3];   // [4096,4096] f32
  const float* Wk = (const float*)d_in[4];   // [4096,1024] f32
  const float* Wv = (const float*)d_in[5];   // [4096,1024] f32
  const float* Wo = (const float*)d_in[6];   // [4096,4096] f32
  float* out = (float*)d_out;                // [2048,4096] f32

  // ws_size is fixed per session -> branch is deterministic (graph-safe).
  // big: WT 32MB @0, Att 16MB @32M (48MB).  small: WT 16MB @0, Att @16M (32MB).
  const int NP = (ws_size >= (size_t)50331648) ? 4096 : 2048;  // weight-panel width
  char* ws = (char*)d_ws;
  u16* WT  = (u16*)ws;
  u16* Att = (u16*)(ws + (NP == 4096 ? 33554432 : 16777216));
  // d_out hosts bf16 intermediates until gemmO overwrites it (stream-ordered):
  u16* Qb  = (u16*)d_out;                    // 16 MB  (rows 0..1023 of f32 out)
  u16* Kb  = (u16*)((char*)d_out + 16777216);  // 4 MB
  u16* VTb = (u16*)((char*)d_out + 20971520);  // 4 MB (V^T [1024][2048])

  const dim3 b256(256);

  // Q projection (panelled over N)
  for (int p = 0; p < 4096; p += NP) {
    transpose_w<<<dim3(NP / 32, 128), b256, 0, stream>>>(Wq, WT, 4096, 4096, p);
    gemm_bt<1, 0, 0><<<dim3(16, NP / 128), b256, 0, stream>>>(X, WT, Qb + p, 2048, NP, 4096, 4096);
  }
  // K projection
  transpose_w<<<dim3(32, 128), b256, 0, stream>>>(Wk, WT, 4096, 1024, 0);
  gemm_bt<1, 0, 0><<<dim3(16, 8), b256, 0, stream>>>(X, WT, Kb, 2048, 1024, 4096, 1024);
  // V projection, output transposed -> VTb [1024][2048]
  transpose_w<<<dim3(32, 128), b256, 0, stream>>>(Wv, WT, 4096, 1024, 0);
  gemm_bt<1, 0, 1><<<dim3(16, 8), b256, 0, stream>>>(X, WT, VTb, 2048, 1024, 4096, 2048);

  // RoPE (Q pre-scaled by 1/sqrt(128))
  rope_kernel<<<dim3(2048 * 32 * 64 / 256), b256, 0, stream>>>(Qb, pos, 5, 0.08838834764831845f);
  rope_kernel<<<dim3(2048 * 8 * 64 / 256),  b256, 0, stream>>>(Kb, pos, 3, 1.0f);

  // paired q-tiles: block x = {qb, 31-qb} -> 33 iters/block, perfectly balanced
  flash_kernel<<<dim3(16, 32), b256, 0, stream>>>(Qb, Kb, VTb, Att);

  // O projection (reads Att bf16 + WT panels, writes f32 out; Qb/Kb/VTb dead)
  for (int p = 0; p < 4096; p += NP) {
    transpose_w<<<dim3(NP / 32, 128), b256, 0, stream>>>(Wo, WT, 4096, 4096, p);
    gemm_bt<0, 1, 0><<<dim3(16, NP / 128), b256, 0, stream>>>(Att, WT, out + p, 2048, NP, 4096, 4096);
  }
}

// Round 4
// 691.520 us; speedup vs baseline: 1.3469x; 1.2336x over previous
//
#include <hip/hip_runtime.h>

typedef unsigned short u16;
typedef __attribute__((ext_vector_type(8))) __bf16 bf16x8;
typedef __attribute__((ext_vector_type(8))) unsigned short u16x8;
typedef __attribute__((ext_vector_type(4))) float f32x4;

#define AS1 __attribute__((address_space(1)))
#define AS3 __attribute__((address_space(3)))

__device__ __forceinline__ void load_lds16(const void* g, void* l) {
  __builtin_amdgcn_global_load_lds((const AS1 unsigned int*)g,
                                   (AS3 unsigned int*)l, 16, 0, 0);
}

__device__ __forceinline__ float bf2f(u16 u) {
  unsigned int x = ((unsigned int)u) << 16;
  return __builtin_bit_cast(float, x);
}
__device__ __forceinline__ u16 f2bf(float f) {
  unsigned int x = __builtin_bit_cast(unsigned int, f);
  x += 0x7fffu + ((x >> 16) & 1u);
  return (u16)(x >> 16);
}
// load 8 consecutive f32, RNE-convert to bf16x8
__device__ __forceinline__ bf16x8 cvt8(const float* p) {
  f32x4 a = *(const f32x4*)p;
  f32x4 b = *(const f32x4*)(p + 4);
  u16x8 r;
#pragma unroll
  for (int j = 0; j < 4; ++j) { r[j] = f2bf(a[j]); r[4 + j] = f2bf(b[j]); }
  return __builtin_bit_cast(bf16x8, r);
}

// ---------------------------------------------------------------- f32 -> bf16 bulk convert
__global__ __launch_bounds__(256) void cvt_bf16_kernel(const float* __restrict__ in,
                                                       u16* __restrict__ out) {
  const int i = (blockIdx.x * 256 + threadIdx.x) * 8;
  *(bf16x8*)&out[i] = cvt8(in + i);
}

// ---------------------------------------------------------------- weight transpose
// out[c - col0][r] = bf16(in[r*C + c])  for c in [col0, col0+Cpanel)
__global__ __launch_bounds__(256) void transpose_w(const float* __restrict__ in,
                                                   u16* __restrict__ out,
                                                   int R, int C, int col0) {
  __shared__ u16 tile[32][33];
  const int tx = threadIdx.x & 31, ty = threadIdx.x >> 5;
  const int c0 = blockIdx.x * 32, r0 = blockIdx.y * 32;  // c0: panel-local col
#pragma unroll
  for (int j = ty; j < 32; j += 8)
    tile[j][tx] = f2bf(in[(size_t)(r0 + j) * C + col0 + c0 + tx]);
  __syncthreads();
#pragma unroll
  for (int j = ty; j < 32; j += 8)
    out[(size_t)(c0 + j) * R + r0 + tx] = tile[tx][j];
}

// ---------------------------------------------------------------- GEMM small (m97 structure)
// kept for K/V projections (N=1024). A bf16 via global_load_lds.
template <int AF32, int OF32, int TR>
__global__ __launch_bounds__(256) void gemm_bt(const void* __restrict__ Av,
                                               const u16* __restrict__ Bt,
                                               void* __restrict__ Cv,
                                               int M, int N, int K, int ldC) {
  __shared__ __align__(16) u16 As[128 * 32];
  __shared__ __align__(16) u16 Bs[128 * 32];
  const int tid = threadIdx.x, lane = tid & 63, w = tid >> 6;
  const int quad = lane >> 4, c16 = lane & 15;
  const int rw = lane >> 2, c4 = lane & 3;
  const int bm = blockIdx.x * 128, bn = blockIdx.y * 128;
  const int wm = (w >> 1) * 64, wn = (w & 1) * 64;

  f32x4 acc[4][4] = {};

  const u16* Ab = (const u16*)Av;
  const float* Af = (const float*)Av;
  const u16* Ag0 = Ab + (size_t)(bm + w * 16 + rw) * K + c4 * 8;
  const u16* Ag1 = Ag0 + (size_t)64 * K;
  const float* Af0 = Af + (size_t)(bm + w * 16 + rw) * K + c4 * 8;
  const float* Af1 = Af0 + (size_t)64 * K;
  const u16* Bg0 = Bt + (size_t)(bn + w * 16 + rw) * K + c4 * 8;
  const u16* Bg1 = Bg0 + (size_t)64 * K;
  u16* As0 = &As[(w * 16) * 32];
  u16* As1 = &As[(64 + w * 16) * 32];
  u16* Bs0 = &Bs[(w * 16) * 32];
  u16* Bs1 = &Bs[(64 + w * 16) * 32];

  for (int k0 = 0; k0 < K; k0 += 32) {
    bf16x8 va0, va1;
    if (AF32) {
      va0 = cvt8(Af0 + k0);
      va1 = cvt8(Af1 + k0);
    } else {
      load_lds16(Ag0 + k0, As0);
      load_lds16(Ag1 + k0, As1);
    }
    load_lds16(Bg0 + k0, Bs0);
    load_lds16(Bg1 + k0, Bs1);
    if (AF32) {
      *(bf16x8*)&As[(w * 16 + rw) * 32 + c4 * 8] = va0;
      *(bf16x8*)&As[(64 + w * 16 + rw) * 32 + c4 * 8] = va1;
    }
    __syncthreads();
    bf16x8 a[4], b[4];
#pragma unroll
    for (int mt = 0; mt < 4; ++mt)
      a[mt] = *(const bf16x8*)&As[(wm + mt * 16 + c16) * 32 + quad * 8];
#pragma unroll
    for (int nt = 0; nt < 4; ++nt)
      b[nt] = *(const bf16x8*)&Bs[(wn + nt * 16 + c16) * 32 + quad * 8];
#pragma unroll
    for (int mt = 0; mt < 4; ++mt)
#pragma unroll
      for (int nt = 0; nt < 4; ++nt)
        acc[mt][nt] = __builtin_amdgcn_mfma_f32_16x16x32_bf16(a[mt], b[nt], acc[mt][nt], 0, 0, 0);
    __syncthreads();
  }
#pragma unroll
  for (int mt = 0; mt < 4; ++mt)
#pragma unroll
    for (int nt = 0; nt < 4; ++nt)
#pragma unroll
      for (int r = 0; r < 4; ++r) {
        const int row = bm + wm + mt * 16 + quad * 4 + r;
        const int col = bn + wn + nt * 16 + c16;
        const size_t idx = TR ? (size_t)col * ldC + row : (size_t)row * ldC + col;
        if (OF32)
          ((float*)Cv)[idx] = acc[mt][nt][r];
        else
          ((u16*)Cv)[idx] = f2bf(acc[mt][nt][r]);
      }
}

// ---------------------------------------------------------------- GEMM big (deep pipeline)
// C[M,N] = A[M,K] @ Bt[N,K]^T, A,Bt bf16.  BM=128, BN=256, BK=64, 512 thr =
// 8 waves (2M x 4N, wave owns 64x64).  Triple-buffered LDS (144 KiB), ONE
// __syncthreads per K-tile, staging issued 2 tiles ahead -> each DMA has a
// full compute iteration (~1300 cyc) before any vmcnt(0) drain touches it.
// LDS tiles row-major [row][64] u16 (128 B rows) with XOR swizzle: staging
// pre-swizzles the GLOBAL source (slot s = (l&7)^(l>>3); gload_lds dest stays
// linear, rule #21), reads XOR byte ^ ((row&7)<<4) -> 16 c16-lanes spread
// over all 8 bank-slots (2/slot = free).
__device__ __forceinline__ void stage_tile2(const u16* Ag, const u16* Bg,
                                            u16* Asb, u16* Bsb, int w, int K,
                                            int k0) {
#pragma unroll
  for (int j = 0; j < 2; ++j)
    load_lds16(Ag + (size_t)j * 64 * K + k0, Asb + j * 4096 + w * 512);
#pragma unroll
  for (int j = 0; j < 4; ++j)
    load_lds16(Bg + (size_t)j * 64 * K + k0, Bsb + j * 4096 + w * 512);
}

template <int OF32>
__global__ __launch_bounds__(512, 2) void gemm2(const u16* __restrict__ A,
                                                const u16* __restrict__ Bt,
                                                void* __restrict__ Cv,
                                                int K, int ldC) {
  __shared__ __align__(16) u16 As[3][128 * 64];  // 48 KiB
  __shared__ __align__(16) u16 Bs[3][256 * 64];  // 96 KiB
  const int tid = threadIdx.x, lane = tid & 63, w = tid >> 6;
  const int quad = lane >> 4, c16 = lane & 15;
  const int bm = blockIdx.x * 128, bn = blockIdx.y * 256;
  const int wm = (w >> 2) * 64, wn = (w & 3) * 64;

  // staging source addresses: lane l covers (row = j*64 + w*8 + (l>>3),
  // logical k-slot s = (l&7)^(l>>3)); LDS dest linear -> slot lands at
  // chunk (l&7) = s ^ (row&7)  (the read-side involution).
  const int l3 = lane >> 3, l7 = lane & 7;
  const int ss = l7 ^ l3;
  const u16* Ag = A + (size_t)(bm + w * 8 + l3) * K + ss * 8;
  const u16* Bg = Bt + (size_t)(bn + w * 8 + l3) * K + ss * 8;
  const int sx = (c16 & 7) << 4;  // read-side byte XOR

  f32x4 acc[4][4] = {};
  const int NT = K >> 6;

  stage_tile2(Ag, Bg, As[0], Bs[0], w, K, 0);
  stage_tile2(Ag, Bg, As[1], Bs[1], w, K, 64);
  int bc = 0;  // kt % 3
  for (int kt = 0; kt < NT; ++kt) {
    __syncthreads();  // drains vmcnt: stage(kt) landed (issued >=1 iter ago)
    const int bp = bc + 2 >= 3 ? bc - 1 : bc + 2;  // (kt+2) % 3
    if (kt + 2 < NT) stage_tile2(Ag, Bg, As[bp], Bs[bp], w, K, (kt + 2) << 6);

    const u16* Ab = As[bc];
    const u16* Bb = Bs[bc];
    bf16x8 a[4][2], b[4][2];
#pragma unroll
    for (int mt = 0; mt < 4; ++mt)
#pragma unroll
      for (int kc = 0; kc < 2; ++kc) {
        const int row = wm + mt * 16 + c16;
        a[mt][kc] = *(const bf16x8*)&Ab[(row * 128 + ((((kc * 4 + quad) << 4)) ^ sx)) >> 1];
      }
#pragma unroll
    for (int nt = 0; nt < 4; ++nt)
#pragma unroll
      for (int kc = 0; kc < 2; ++kc) {
        const int row = wn + nt * 16 + c16;
        b[nt][kc] = *(const bf16x8*)&Bb[(row * 128 + ((((kc * 4 + quad) << 4)) ^ sx)) >> 1];
      }
#pragma unroll
    for (int kc = 0; kc < 2; ++kc)
#pragma unroll
      for (int mt = 0; mt < 4; ++mt)
#pragma unroll
        for (int nt = 0; nt < 4; ++nt)
          acc[mt][nt] = __builtin_amdgcn_mfma_f32_16x16x32_bf16(a[mt][kc], b[nt][kc], acc[mt][nt], 0, 0, 0);
    bc = bc == 2 ? 0 : bc + 1;
  }
#pragma unroll
  for (int mt = 0; mt < 4; ++mt)
#pragma unroll
    for (int nt = 0; nt < 4; ++nt)
#pragma unroll
      for (int r = 0; r < 4; ++r) {
        const int row = bm + wm + mt * 16 + quad * 4 + r;
        const int col = bn + wn + nt * 16 + c16;
        if (OF32)
          ((float*)Cv)[(size_t)row * ldC + col] = acc[mt][nt][r];
        else
          ((u16*)Cv)[(size_t)row * ldC + col] = f2bf(acc[mt][nt][r]);
      }
}

// ---------------------------------------------------------------- RoPE (in place, bf16)
__global__ void rope_kernel(u16* __restrict__ buf, const int* __restrict__ pos,
                            int log2nh, float oscale) {
  const int t = blockIdx.x * 256 + threadIdx.x;
  const int i = t & 63;
  const int h = (t >> 6) & ((1 << log2nh) - 1);
  const int s = t >> (6 + log2nh);
  const int nh = 1 << log2nh;
  const float p = (float)pos[s];
  const float invf = exp2f((float)i * -0.20762051915861040f);  // 10000^(-i/64)
  const float ang = p * invf;
  const float cn = cosf(ang), sn = sinf(ang);
  const size_t i1 = (size_t)s * (nh * 128) + h * 128 + i;
  const size_t i2 = i1 + 64;
  const float x1 = bf2f(buf[i1]), x2 = bf2f(buf[i2]);
  buf[i1] = f2bf((x1 * cn - x2 * sn) * oscale);
  buf[i2] = f2bf((x2 * cn + x1 * sn) * oscale);
}

// ---------------------------------------------------------------- flash attention
// v2 (verified r2): paired q-tiles, Q direct-to-reg, K/V reg-prefetch,
// XOR-swizzled Ks/Vts.
__global__ __launch_bounds__(256, 2) void flash_kernel(const u16* __restrict__ Q,
                                                       const u16* __restrict__ K,
                                                       const u16* __restrict__ VT,
                                                       u16* __restrict__ O) {
  __shared__ __align__(16) u16 Ks[64 * 128];   // [key][k], swizzled
  __shared__ __align__(16) u16 Vts[128 * 64];  // [d][key], swizzled
  __shared__ __align__(16) u16 Ps[4][16 * 72]; // per-wave P tile (2-way = free)
  const int h = blockIdx.y, kvh = h >> 2;
  const int tid = threadIdx.x, lane = tid & 63, w = tid >> 6;
  const int quad = lane >> 4, c16 = lane & 15;
  const int rw = lane >> 2, c4 = lane & 3;
  const int sw = (rw & 7) << 3;
  const int sr = (c16 & 7) << 3;

  for (int half = 0; half < 2; ++half) {
    const int qb = half ? (31 - blockIdx.x) : blockIdx.x;

    bf16x8 aq[4];
#pragma unroll
    for (int kc = 0; kc < 4; ++kc)
      aq[kc] = *(const bf16x8*)&Q[(size_t)(qb * 64 + w * 16 + c16) * 4096 + h * 128 + kc * 32 + quad * 8];

    f32x4 acc_o[8] = {};
    float m_run[4], l_run[4];
#pragma unroll
    for (int r = 0; r < 4; ++r) { m_run[r] = -1e30f; l_run[r] = 0.f; }

    bf16x8 kc_[4], vc_[4];
#pragma unroll
    for (int p = 0; p < 4; ++p) {
      kc_[p] = *(const bf16x8*)&K[(size_t)(w * 16 + rw) * 1024 + kvh * 128 + p * 32 + c4 * 8];
      const int d = (p & 1) * 64 + w * 16 + rw;
      vc_[p] = *(const bf16x8*)&VT[(size_t)(kvh * 128 + d) * 2048 + (p >> 1) * 32 + c4 * 8];
    }

    for (int t = 0; t <= qb; ++t) {
      __syncthreads();
      const int key = w * 16 + rw;
#pragma unroll
      for (int p = 0; p < 4; ++p) {
        *(bf16x8*)&Ks[key * 128 + ((p * 32 + c4 * 8) ^ sw)] = kc_[p];
        const int d = (p & 1) * 64 + w * 16 + rw;
        *(bf16x8*)&Vts[d * 64 + ((((p >> 1) * 32 + c4 * 8)) ^ ((d & 7) << 3))] = vc_[p];
      }
      __syncthreads();
      if (t < qb) {
#pragma unroll
        for (int p = 0; p < 4; ++p) {
          kc_[p] = *(const bf16x8*)&K[(size_t)((t + 1) * 64 + w * 16 + rw) * 1024 + kvh * 128 + p * 32 + c4 * 8];
          const int d = (p & 1) * 64 + w * 16 + rw;
          vc_[p] = *(const bf16x8*)&VT[(size_t)(kvh * 128 + d) * 2048 + (t + 1) * 64 + (p >> 1) * 32 + c4 * 8];
        }
      }

      f32x4 sacc[4];
#pragma unroll
      for (int nt = 0; nt < 4; ++nt) {
        f32x4 s = {0.f, 0.f, 0.f, 0.f};
#pragma unroll
        for (int kc = 0; kc < 4; ++kc) {
          bf16x8 bk = *(const bf16x8*)&Ks[(nt * 16 + c16) * 128 + ((kc * 32 + quad * 8) ^ sr)];
          s = __builtin_amdgcn_mfma_f32_16x16x32_bf16(aq[kc], bk, s, 0, 0, 0);
        }
        sacc[nt] = s;
      }
      if (t == qb) {
#pragma unroll
        for (int nt = 0; nt < 4; ++nt)
#pragma unroll
          for (int r = 0; r < 4; ++r)
            if (nt * 16 + c16 > w * 16 + quad * 4 + r) sacc[nt][r] = -1e30f;
      }
      float al[4];
#pragma unroll
      for (int r = 0; r < 4; ++r) {
        float mx = fmaxf(fmaxf(sacc[0][r], sacc[1][r]), fmaxf(sacc[2][r], sacc[3][r]));
#pragma unroll
        for (int off = 1; off < 16; off <<= 1) mx = fmaxf(mx, __shfl_xor(mx, off));
        const float nm = fmaxf(m_run[r], mx);
        al[r] = __expf(m_run[r] - nm);
        m_run[r] = nm;
        float sum = 0.f;
#pragma unroll
        for (int nt = 0; nt < 4; ++nt) {
          const float pv = __expf(sacc[nt][r] - nm);
          sacc[nt][r] = pv;
          sum += pv;
        }
#pragma unroll
        for (int off = 1; off < 16; off <<= 1) sum += __shfl_xor(sum, off);
        l_run[r] = l_run[r] * al[r] + sum;
      }
#pragma unroll
      for (int dt = 0; dt < 8; ++dt)
#pragma unroll
        for (int r = 0; r < 4; ++r) acc_o[dt][r] *= al[r];
#pragma unroll
      for (int nt = 0; nt < 4; ++nt)
#pragma unroll
        for (int r = 0; r < 4; ++r)
          Ps[w][(quad * 4 + r) * 72 + nt * 16 + c16] = f2bf(sacc[nt][r]);
      asm volatile("s_waitcnt lgkmcnt(0)" ::: "memory");
      bf16x8 ap[2];
#pragma unroll
      for (int kc = 0; kc < 2; ++kc)
        ap[kc] = *(const bf16x8*)&Ps[w][c16 * 72 + kc * 32 + quad * 8];
#pragma unroll
      for (int dt = 0; dt < 8; ++dt)
#pragma unroll
        for (int kc = 0; kc < 2; ++kc) {
          bf16x8 bv = *(const bf16x8*)&Vts[(dt * 16 + c16) * 64 + ((kc * 32 + quad * 8) ^ sr)];
          acc_o[dt] = __builtin_amdgcn_mfma_f32_16x16x32_bf16(ap[kc], bv, acc_o[dt], 0, 0, 0);
        }
    }
#pragma unroll
    for (int r = 0; r < 4; ++r) {
      const float inv = 1.0f / l_run[r];
      const int row = qb * 64 + w * 16 + quad * 4 + r;
#pragma unroll
      for (int dt = 0; dt < 8; ++dt)
        O[(size_t)row * 4096 + h * 128 + dt * 16 + c16] = f2bf(acc_o[dt][r] * inv);
    }
  }
}

// ---------------------------------------------------------------- launch
extern "C" void kernel_launch(void* const* d_in, const int* in_sizes, int n_in,
                              void* d_out, int out_size, void* d_ws, size_t ws_size,
                              hipStream_t stream) {
  const float* X  = (const float*)d_in[0];   // [2048,4096] f32
  const int* pos  = (const int*)d_in[2];     // causal mask (d_in[1]) applied analytically
  const float* Wq = (const float*)d_in[3];   // [4096,4096] f32
  const float* Wk = (const float*)d_in[4];   // [4096,1024] f32
  const float* Wv = (const float*)d_in[5];   // [4096,1024] f32
  const float* Wo = (const float*)d_in[6];   // [4096,4096] f32
  float* out = (float*)d_out;                // [2048,4096] f32

  // ws layout (big): WT 32MB @0, Att 16MB @32M.  small: WT 16MB @0, Att @16M.
  // Xb (bf16 X, 16MB) shares the Att slot — Att is only written by flash,
  // which runs after every consumer of Xb (Q/K/V projections).
  const int NP = (ws_size >= (size_t)50331648) ? 4096 : 2048;  // weight-panel width
  char* ws = (char*)d_ws;
  u16* WT  = (u16*)ws;
  u16* Att = (u16*)(ws + (NP == 4096 ? 33554432 : 16777216));
  u16* Xb  = Att;                            // dead before flash writes Att
  // d_out hosts bf16 intermediates until gemmO overwrites it (stream-ordered):
  u16* Qb  = (u16*)d_out;                    // 16 MB
  u16* Kb  = (u16*)((char*)d_out + 16777216);  // 4 MB
  u16* VTb = (u16*)((char*)d_out + 20971520);  // 4 MB (V^T [1024][2048])

  const dim3 b256(256), b512(512);

  // X -> bf16 once (A operand for all projections)
  cvt_bf16_kernel<<<dim3(4096), b256, 0, stream>>>(X, Xb);

  // Q projection (panelled over N)
  for (int p = 0; p < 4096; p += NP) {
    transpose_w<<<dim3(NP / 32, 128), b256, 0, stream>>>(Wq, WT, 4096, 4096, p);
    gemm2<0><<<dim3(16, NP / 256), b512, 0, stream>>>(Xb, WT, Qb + p, 4096, 4096);
  }
  // K projection
  transpose_w<<<dim3(32, 128), b256, 0, stream>>>(Wk, WT, 4096, 1024, 0);
  gemm_bt<0, 0, 0><<<dim3(16, 8), b256, 0, stream>>>(Xb, WT, Kb, 2048, 1024, 4096, 1024);
  // V projection, output transposed -> VTb [1024][2048]
  transpose_w<<<dim3(32, 128), b256, 0, stream>>>(Wv, WT, 4096, 1024, 0);
  gemm_bt<0, 0, 1><<<dim3(16, 8), b256, 0, stream>>>(Xb, WT, VTb, 2048, 1024, 4096, 2048);

  // RoPE (Q pre-scaled by 1/sqrt(128))
  rope_kernel<<<dim3(2048 * 32 * 64 / 256), b256, 0, stream>>>(Qb, pos, 5, 0.08838834764831845f);
  rope_kernel<<<dim3(2048 * 8 * 64 / 256),  b256, 0, stream>>>(Kb, pos, 3, 1.0f);

  // paired q-tiles: block x = {qb, 31-qb} -> 33 iters/block, balanced
  flash_kernel<<<dim3(16, 32), b256, 0, stream>>>(Qb, Kb, VTb, Att);

  // O projection (reads Att bf16 + WT panels, writes f32 out)
  for (int p = 0; p < 4096; p += NP) {
    transpose_w<<<dim3(NP / 32, 128), b256, 0, stream>>>(Wo, WT, 4096, 4096, p);
    gemm2<1><<<dim3(16, NP / 256), b512, 0, stream>>>(Att, WT, out + p, 4096, 4096);
  }
}

// Round 5
// 598.869 us; speedup vs baseline: 1.5552x; 1.1547x over previous
//
#include <hip/hip_runtime.h>

typedef unsigned short u16;
typedef __attribute__((ext_vector_type(8))) __bf16 bf16x8;
typedef __attribute__((ext_vector_type(8))) unsigned short u16x8;
typedef __attribute__((ext_vector_type(4))) float f32x4;

#define AS1 __attribute__((address_space(1)))
#define AS3 __attribute__((address_space(3)))

__device__ __forceinline__ void load_lds16(const void* g, void* l) {
  __builtin_amdgcn_global_load_lds((const AS1 unsigned int*)g,
                                   (AS3 unsigned int*)l, 16, 0, 0);
}

__device__ __forceinline__ float bf2f(u16 u) {
  unsigned int x = ((unsigned int)u) << 16;
  return __builtin_bit_cast(float, x);
}
__device__ __forceinline__ u16 f2bf(float f) {
  unsigned int x = __builtin_bit_cast(unsigned int, f);
  x += 0x7fffu + ((x >> 16) & 1u);
  return (u16)(x >> 16);
}
// load 8 consecutive f32, RNE-convert to bf16x8
__device__ __forceinline__ bf16x8 cvt8(const float* p) {
  f32x4 a = *(const f32x4*)p;
  f32x4 b = *(const f32x4*)(p + 4);
  u16x8 r;
#pragma unroll
  for (int j = 0; j < 4; ++j) { r[j] = f2bf(a[j]); r[4 + j] = f2bf(b[j]); }
  return __builtin_bit_cast(bf16x8, r);
}

// ---------------------------------------------------------------- f32 -> bf16 bulk convert
__global__ __launch_bounds__(256) void cvt_bf16_kernel(const float* __restrict__ in,
                                                       u16* __restrict__ out) {
  const int i = (blockIdx.x * 256 + threadIdx.x) * 8;
  *(bf16x8*)&out[i] = cvt8(in + i);
}

// ---------------------------------------------------------------- weight transpose
// out[c - col0][r] = bf16(in[r*C + c])  for c in [col0, col0+Cpanel)
__global__ __launch_bounds__(256) void transpose_w(const float* __restrict__ in,
                                                   u16* __restrict__ out,
                                                   int R, int C, int col0) {
  __shared__ u16 tile[32][33];
  const int tx = threadIdx.x & 31, ty = threadIdx.x >> 5;
  const int c0 = blockIdx.x * 32, r0 = blockIdx.y * 32;  // c0: panel-local col
#pragma unroll
  for (int j = ty; j < 32; j += 8)
    tile[j][tx] = f2bf(in[(size_t)(r0 + j) * C + col0 + c0 + tx]);
  __syncthreads();
#pragma unroll
  for (int j = ty; j < 32; j += 8)
    out[(size_t)(c0 + j) * R + r0 + tx] = tile[tx][j];
}

// ---------------------------------------------------------------- fused K|V projection
// C = Xb[2048,4096] @ WTkv[2048,4096]^T.  cols 0..1023 -> Kb [2048,1024];
// cols 1024..2047 -> VTb [1024,2048] (transposed).  Grid (16,16) = 256 blocks
// = full machine (replaces two half-machine launches).  m97 structure.
__global__ __launch_bounds__(256) void gemm_kv(const u16* __restrict__ A,
                                               const u16* __restrict__ Bt,
                                               u16* __restrict__ Kb,
                                               u16* __restrict__ VTb) {
  const int K = 4096;
  __shared__ __align__(16) u16 As[128 * 32];
  __shared__ __align__(16) u16 Bs[128 * 32];
  const int tid = threadIdx.x, lane = tid & 63, w = tid >> 6;
  const int quad = lane >> 4, c16 = lane & 15;
  const int rw = lane >> 2, c4 = lane & 3;
  const int bm = blockIdx.x * 128, bn = blockIdx.y * 128;
  const int wm = (w >> 1) * 64, wn = (w & 1) * 64;

  f32x4 acc[4][4] = {};

  const u16* Ag0 = A + (size_t)(bm + w * 16 + rw) * K + c4 * 8;
  const u16* Ag1 = Ag0 + (size_t)64 * K;
  const u16* Bg0 = Bt + (size_t)(bn + w * 16 + rw) * K + c4 * 8;
  const u16* Bg1 = Bg0 + (size_t)64 * K;
  u16* As0 = &As[(w * 16) * 32];
  u16* As1 = &As[(64 + w * 16) * 32];
  u16* Bs0 = &Bs[(w * 16) * 32];
  u16* Bs1 = &Bs[(64 + w * 16) * 32];

  for (int k0 = 0; k0 < K; k0 += 32) {
    load_lds16(Ag0 + k0, As0);
    load_lds16(Ag1 + k0, As1);
    load_lds16(Bg0 + k0, Bs0);
    load_lds16(Bg1 + k0, Bs1);
    __syncthreads();
    bf16x8 a[4], b[4];
#pragma unroll
    for (int mt = 0; mt < 4; ++mt)
      a[mt] = *(const bf16x8*)&As[(wm + mt * 16 + c16) * 32 + quad * 8];
#pragma unroll
    for (int nt = 0; nt < 4; ++nt)
      b[nt] = *(const bf16x8*)&Bs[(wn + nt * 16 + c16) * 32 + quad * 8];
#pragma unroll
    for (int mt = 0; mt < 4; ++mt)
#pragma unroll
      for (int nt = 0; nt < 4; ++nt)
        acc[mt][nt] = __builtin_amdgcn_mfma_f32_16x16x32_bf16(a[mt], b[nt], acc[mt][nt], 0, 0, 0);
    __syncthreads();
  }
#pragma unroll
  for (int mt = 0; mt < 4; ++mt)
#pragma unroll
    for (int nt = 0; nt < 4; ++nt)
#pragma unroll
      for (int r = 0; r < 4; ++r) {
        const int row = bm + wm + mt * 16 + quad * 4 + r;
        const int col = bn + wn + nt * 16 + c16;
        if (bn < 1024)  // block-uniform
          Kb[(size_t)row * 1024 + col] = f2bf(acc[mt][nt][r]);
        else
          VTb[(size_t)(col - 1024) * 2048 + row] = f2bf(acc[mt][nt][r]);
      }
}

// ---------------------------------------------------------------- GEMM big (deep pipeline)
// C[M,N] = A[M,K] @ Bt[N,K]^T, A,Bt bf16.  BM=128, BN=256, BK=64, 512 thr =
// 8 waves (2M x 4N, wave owns 64x64).  Triple-buffered LDS (144 KiB), ONE
// __syncthreads per K-tile, staging issued 2 tiles ahead.  LDS row-major
// [row][64] u16 with XOR swizzle via pre-swizzled global source (rule #21).
__device__ __forceinline__ void stage_tile2(const u16* Ag, const u16* Bg,
                                            u16* Asb, u16* Bsb, int w, int K,
                                            int k0) {
#pragma unroll
  for (int j = 0; j < 2; ++j)
    load_lds16(Ag + (size_t)j * 64 * K + k0, Asb + j * 4096 + w * 512);
#pragma unroll
  for (int j = 0; j < 4; ++j)
    load_lds16(Bg + (size_t)j * 64 * K + k0, Bsb + j * 4096 + w * 512);
}

template <int OF32>
__global__ __launch_bounds__(512, 2) void gemm2(const u16* __restrict__ A,
                                                const u16* __restrict__ Bt,
                                                void* __restrict__ Cv,
                                                int K, int ldC) {
  __shared__ __align__(16) u16 As[3][128 * 64];  // 48 KiB
  __shared__ __align__(16) u16 Bs[3][256 * 64];  // 96 KiB
  const int tid = threadIdx.x, lane = tid & 63, w = tid >> 6;
  const int quad = lane >> 4, c16 = lane & 15;
  const int bm = blockIdx.x * 128, bn = blockIdx.y * 256;
  const int wm = (w >> 2) * 64, wn = (w & 3) * 64;

  const int l3 = lane >> 3, l7 = lane & 7;
  const int ss = l7 ^ l3;
  const u16* Ag = A + (size_t)(bm + w * 8 + l3) * K + ss * 8;
  const u16* Bg = Bt + (size_t)(bn + w * 8 + l3) * K + ss * 8;
  const int sx = (c16 & 7) << 4;  // read-side byte XOR

  f32x4 acc[4][4] = {};
  const int NT = K >> 6;

  stage_tile2(Ag, Bg, As[0], Bs[0], w, K, 0);
  stage_tile2(Ag, Bg, As[1], Bs[1], w, K, 64);
  int bc = 0;  // kt % 3
  for (int kt = 0; kt < NT; ++kt) {
    __syncthreads();  // drains vmcnt: stage(kt) landed (issued >=1 iter ago)
    const int bp = bc + 2 >= 3 ? bc - 1 : bc + 2;  // (kt+2) % 3
    if (kt + 2 < NT) stage_tile2(Ag, Bg, As[bp], Bs[bp], w, K, (kt + 2) << 6);

    const u16* Ab = As[bc];
    const u16* Bb = Bs[bc];
    bf16x8 a[4][2], b[4][2];
#pragma unroll
    for (int mt = 0; mt < 4; ++mt)
#pragma unroll
      for (int kc = 0; kc < 2; ++kc) {
        const int row = wm + mt * 16 + c16;
        a[mt][kc] = *(const bf16x8*)&Ab[(row * 128 + ((((kc * 4 + quad) << 4)) ^ sx)) >> 1];
      }
#pragma unroll
    for (int nt = 0; nt < 4; ++nt)
#pragma unroll
      for (int kc = 0; kc < 2; ++kc) {
        const int row = wn + nt * 16 + c16;
        b[nt][kc] = *(const bf16x8*)&Bb[(row * 128 + ((((kc * 4 + quad) << 4)) ^ sx)) >> 1];
      }
#pragma unroll
    for (int kc = 0; kc < 2; ++kc)
#pragma unroll
      for (int mt = 0; mt < 4; ++mt)
#pragma unroll
        for (int nt = 0; nt < 4; ++nt)
          acc[mt][nt] = __builtin_amdgcn_mfma_f32_16x16x32_bf16(a[mt][kc], b[nt][kc], acc[mt][nt], 0, 0, 0);
    bc = bc == 2 ? 0 : bc + 1;
  }
#pragma unroll
  for (int mt = 0; mt < 4; ++mt)
#pragma unroll
    for (int nt = 0; nt < 4; ++nt)
#pragma unroll
      for (int r = 0; r < 4; ++r) {
        const int row = bm + wm + mt * 16 + quad * 4 + r;
        const int col = bn + wn + nt * 16 + c16;
        if (OF32)
          ((float*)Cv)[(size_t)row * ldC + col] = acc[mt][nt][r];
        else
          ((u16*)Cv)[(size_t)row * ldC + col] = f2bf(acc[mt][nt][r]);
      }
}

// ---------------------------------------------------------------- RoPE (in place, bf16)
__global__ void rope_kernel(u16* __restrict__ buf, const int* __restrict__ pos,
                            int log2nh, float oscale) {
  const int t = blockIdx.x * 256 + threadIdx.x;
  const int i = t & 63;
  const int h = (t >> 6) & ((1 << log2nh) - 1);
  const int s = t >> (6 + log2nh);
  const int nh = 1 << log2nh;
  const float p = (float)pos[s];
  const float invf = exp2f((float)i * -0.20762051915861040f);  // 10000^(-i/64)
  const float ang = p * invf;
  const float cn = cosf(ang), sn = sinf(ang);
  const size_t i1 = (size_t)s * (nh * 128) + h * 128 + i;
  const size_t i2 = i1 + 64;
  const float x1 = bf2f(buf[i1]), x2 = bf2f(buf[i2]);
  buf[i1] = f2bf((x1 * cn - x2 * sn) * oscale);
  buf[i2] = f2bf((x2 * cn + x1 * sn) * oscale);
}

// ---------------------------------------------------------------- flash attention
// v3: UNPAIRED grid (32 heads x 32 qtiles), LPT order (qb = 31 - blockIdx.y:
// longest blocks dispatch first, short ones pack the tail), 3 blocks/CU by
// LDS (41984 B), s_setprio around MFMA clusters (T5).  Q direct-to-reg, K/V
// reg-prefetch, swizzled Ks/Vts (kept from verified v2).
__global__ __launch_bounds__(256, 2) void flash_kernel(const u16* __restrict__ Q,
                                                       const u16* __restrict__ K,
                                                       const u16* __restrict__ VT,
                                                       u16* __restrict__ O) {
  __shared__ __align__(16) u16 Ks[64 * 128];   // [key][k], swizzled
  __shared__ __align__(16) u16 Vts[128 * 64];  // [d][key], swizzled
  __shared__ __align__(16) u16 Ps[4][16 * 72]; // per-wave P tile
  const int h = blockIdx.x, kvh = h >> 2;
  const int qb = 31 - blockIdx.y;  // LPT: long blocks first
  const int tid = threadIdx.x, lane = tid & 63, w = tid >> 6;
  const int quad = lane >> 4, c16 = lane & 15;
  const int rw = lane >> 2, c4 = lane & 3;
  const int sw = (rw & 7) << 3;
  const int sr = (c16 & 7) << 3;

  bf16x8 aq[4];
#pragma unroll
  for (int kc = 0; kc < 4; ++kc)
    aq[kc] = *(const bf16x8*)&Q[(size_t)(qb * 64 + w * 16 + c16) * 4096 + h * 128 + kc * 32 + quad * 8];

  f32x4 acc_o[8] = {};
  float m_run[4], l_run[4];
#pragma unroll
  for (int r = 0; r < 4; ++r) { m_run[r] = -1e30f; l_run[r] = 0.f; }

  bf16x8 kc_[4], vc_[4];
#pragma unroll
  for (int p = 0; p < 4; ++p) {
    kc_[p] = *(const bf16x8*)&K[(size_t)(w * 16 + rw) * 1024 + kvh * 128 + p * 32 + c4 * 8];
    const int d = (p & 1) * 64 + w * 16 + rw;
    vc_[p] = *(const bf16x8*)&VT[(size_t)(kvh * 128 + d) * 2048 + (p >> 1) * 32 + c4 * 8];
  }

  for (int t = 0; t <= qb; ++t) {
    __syncthreads();
    const int key = w * 16 + rw;
#pragma unroll
    for (int p = 0; p < 4; ++p) {
      *(bf16x8*)&Ks[key * 128 + ((p * 32 + c4 * 8) ^ sw)] = kc_[p];
      const int d = (p & 1) * 64 + w * 16 + rw;
      *(bf16x8*)&Vts[d * 64 + ((((p >> 1) * 32 + c4 * 8)) ^ ((d & 7) << 3))] = vc_[p];
    }
    __syncthreads();
    if (t < qb) {
#pragma unroll
      for (int p = 0; p < 4; ++p) {
        kc_[p] = *(const bf16x8*)&K[(size_t)((t + 1) * 64 + w * 16 + rw) * 1024 + kvh * 128 + p * 32 + c4 * 8];
        const int d = (p & 1) * 64 + w * 16 + rw;
        vc_[p] = *(const bf16x8*)&VT[(size_t)(kvh * 128 + d) * 2048 + (t + 1) * 64 + (p >> 1) * 32 + c4 * 8];
      }
    }

    f32x4 sacc[4];
    __builtin_amdgcn_s_setprio(1);
#pragma unroll
    for (int nt = 0; nt < 4; ++nt) {
      f32x4 s = {0.f, 0.f, 0.f, 0.f};
#pragma unroll
      for (int kc = 0; kc < 4; ++kc) {
        bf16x8 bk = *(const bf16x8*)&Ks[(nt * 16 + c16) * 128 + ((kc * 32 + quad * 8) ^ sr)];
        s = __builtin_amdgcn_mfma_f32_16x16x32_bf16(aq[kc], bk, s, 0, 0, 0);
      }
      sacc[nt] = s;
    }
    __builtin_amdgcn_s_setprio(0);
    if (t == qb) {
#pragma unroll
      for (int nt = 0; nt < 4; ++nt)
#pragma unroll
        for (int r = 0; r < 4; ++r)
          if (nt * 16 + c16 > w * 16 + quad * 4 + r) sacc[nt][r] = -1e30f;
    }
    float al[4];
#pragma unroll
    for (int r = 0; r < 4; ++r) {
      float mx = fmaxf(fmaxf(sacc[0][r], sacc[1][r]), fmaxf(sacc[2][r], sacc[3][r]));
#pragma unroll
      for (int off = 1; off < 16; off <<= 1) mx = fmaxf(mx, __shfl_xor(mx, off));
      const float nm = fmaxf(m_run[r], mx);
      al[r] = __expf(m_run[r] - nm);
      m_run[r] = nm;
      float sum = 0.f;
#pragma unroll
      for (int nt = 0; nt < 4; ++nt) {
        const float pv = __expf(sacc[nt][r] - nm);
        sacc[nt][r] = pv;
        sum += pv;
      }
#pragma unroll
      for (int off = 1; off < 16; off <<= 1) sum += __shfl_xor(sum, off);
      l_run[r] = l_run[r] * al[r] + sum;
    }
#pragma unroll
    for (int dt = 0; dt < 8; ++dt)
#pragma unroll
      for (int r = 0; r < 4; ++r) acc_o[dt][r] *= al[r];
#pragma unroll
    for (int nt = 0; nt < 4; ++nt)
#pragma unroll
      for (int r = 0; r < 4; ++r)
        Ps[w][(quad * 4 + r) * 72 + nt * 16 + c16] = f2bf(sacc[nt][r]);
    asm volatile("s_waitcnt lgkmcnt(0)" ::: "memory");
    bf16x8 ap[2];
#pragma unroll
    for (int kc = 0; kc < 2; ++kc)
      ap[kc] = *(const bf16x8*)&Ps[w][c16 * 72 + kc * 32 + quad * 8];
    __builtin_amdgcn_s_setprio(1);
#pragma unroll
    for (int dt = 0; dt < 8; ++dt)
#pragma unroll
      for (int kc = 0; kc < 2; ++kc) {
        bf16x8 bv = *(const bf16x8*)&Vts[(dt * 16 + c16) * 64 + ((kc * 32 + quad * 8) ^ sr)];
        acc_o[dt] = __builtin_amdgcn_mfma_f32_16x16x32_bf16(ap[kc], bv, acc_o[dt], 0, 0, 0);
      }
    __builtin_amdgcn_s_setprio(0);
  }
#pragma unroll
  for (int r = 0; r < 4; ++r) {
    const float inv = 1.0f / l_run[r];
    const int row = qb * 64 + w * 16 + quad * 4 + r;
#pragma unroll
    for (int dt = 0; dt < 8; ++dt)
      O[(size_t)row * 4096 + h * 128 + dt * 16 + c16] = f2bf(acc_o[dt][r] * inv);
  }
}

// ---------------------------------------------------------------- launch
extern "C" void kernel_launch(void* const* d_in, const int* in_sizes, int n_in,
                              void* d_out, int out_size, void* d_ws, size_t ws_size,
                              hipStream_t stream) {
  const float* X  = (const float*)d_in[0];   // [2048,4096] f32
  const int* pos  = (const int*)d_in[2];     // causal mask (d_in[1]) applied analytically
  const float* Wq = (const float*)d_in[3];   // [4096,4096] f32
  const float* Wk = (const float*)d_in[4];   // [4096,1024] f32
  const float* Wv = (const float*)d_in[5];   // [4096,1024] f32
  const float* Wo = (const float*)d_in[6];   // [4096,4096] f32
  float* out = (float*)d_out;                // [2048,4096] f32

  // ws layout (big): WT 32MB @0, Att 16MB @32M.  small: WT 16MB @0, Att @16M.
  // Xb (bf16 X, 16MB) shares the Att slot — dead before flash writes Att.
  const int NP = (ws_size >= (size_t)50331648) ? 4096 : 2048;  // weight-panel width
  char* ws = (char*)d_ws;
  u16* WT  = (u16*)ws;
  u16* Att = (u16*)(ws + (NP == 4096 ? 33554432 : 16777216));
  u16* Xb  = Att;
  // d_out hosts bf16 intermediates until gemmO overwrites it (stream-ordered):
  u16* Qb  = (u16*)d_out;                    // 16 MB
  u16* Kb  = (u16*)((char*)d_out + 16777216);  // 4 MB
  u16* VTb = (u16*)((char*)d_out + 20971520);  // 4 MB (V^T [1024][2048])

  const dim3 b256(256), b512(512);

  // X -> bf16 once (A operand for all projections)
  cvt_bf16_kernel<<<dim3(4096), b256, 0, stream>>>(X, Xb);

  // Q projection (panelled over N)
  for (int p = 0; p < 4096; p += NP) {
    transpose_w<<<dim3(NP / 32, 128), b256, 0, stream>>>(Wq, WT, 4096, 4096, p);
    gemm2<0><<<dim3(16, NP / 256), b512, 0, stream>>>(Xb, WT, Qb + p, 4096, 4096);
  }
  // K|V fused projection: WT rows 0..1023 = Wk^T, rows 1024..2047 = Wv^T
  transpose_w<<<dim3(32, 128), b256, 0, stream>>>(Wk, WT, 4096, 1024, 0);
  transpose_w<<<dim3(32, 128), b256, 0, stream>>>(Wv, WT + (size_t)1024 * 4096, 4096, 1024, 0);
  gemm_kv<<<dim3(16, 16), b256, 0, stream>>>(Xb, WT, Kb, VTb);

  // RoPE (Q pre-scaled by 1/sqrt(128))
  rope_kernel<<<dim3(2048 * 32 * 64 / 256), b256, 0, stream>>>(Qb, pos, 5, 0.08838834764831845f);
  rope_kernel<<<dim3(2048 * 8 * 64 / 256),  b256, 0, stream>>>(Kb, pos, 3, 1.0f);

  // unpaired LPT grid: x = head, y: qb = 31 - y -> longest blocks first
  flash_kernel<<<dim3(32, 32), b256, 0, stream>>>(Qb, Kb, VTb, Att);

  // O projection (reads Att bf16 + WT panels, writes f32 out)
  for (int p = 0; p < 4096; p += NP) {
    transpose_w<<<dim3(NP / 32, 128), b256, 0, stream>>>(Wo, WT, 4096, 4096, p);
    gemm2<1><<<dim3(16, NP / 256), b512, 0, stream>>>(Att, WT, out + p, 4096, 4096);
  }
}